// Round 4
// baseline (95.132 us; speedup 1.0000x reference)
//
#include <hip/hip_runtime.h>
#include <hip/hip_bf16.h>

typedef __attribute__((ext_vector_type(4))) float f4v;
typedef __attribute__((ext_vector_type(16))) float f16v;
typedef __attribute__((ext_vector_type(4))) unsigned short u16x4;
typedef __attribute__((ext_vector_type(8))) unsigned short u16x8;
typedef __attribute__((ext_vector_type(4))) unsigned int u32x4;
typedef __attribute__((ext_vector_type(8))) __bf16 bf16x8;

#define D_MODEL 1024
#define HDIM 64
#define TSEQ 4096
#define QB 32
#define KVB 64
// 1/sqrt(HDIM) * log2(e), folded into Q at projection
#define QSCALE 0.18033688011112042f

__device__ __forceinline__ unsigned short f2bf(float f) {
    union { float f; unsigned u; } v; v.f = f;
    unsigned r = v.u + 0x7FFFu + ((v.u >> 16) & 1u);
    return (unsigned short)(r >> 16);
}
__device__ __forceinline__ float asf(unsigned u) {
    union { unsigned u; float f; } v; v.u = u; return v.f;
}
__device__ __forceinline__ bf16x8 ld8(const unsigned short* p) {
    return __builtin_bit_cast(bf16x8, *(const u16x8*)p);
}
__device__ __forceinline__ f4v mfma16(bf16x8 a, bf16x8 b, f4v c) {
    return __builtin_amdgcn_mfma_f32_16x16x32_bf16(a, b, c, 0, 0, 0);
}
__device__ __forceinline__ f16v mfma32(bf16x8 a, bf16x8 b, f16v c) {
    return __builtin_amdgcn_mfma_f32_32x32x16_bf16(a, b, c, 0, 0, 0);
}
__device__ __forceinline__ unsigned cvtpk(float a, float b) {
    unsigned r;
    asm("v_cvt_pk_bf16_f32 %0, %1, %2" : "=v"(r) : "v"(a), "v"(b));
    return r;
}
__device__ __forceinline__ void pswap(unsigned& a, unsigned& b) {
    asm("v_permlane32_swap_b32 %0, %1" : "+v"(a), "+v"(b));
}

// ---------- W -> fragment-order bf16: Wf[m][kstep(32)][nf(4)][lane(64)][8] ----------
// element = W[m][k = kstep*32 + 8*(lane>>4) + j][n = nf*16 + (lane&15)]
__global__ void prep_wf(const float* __restrict__ Wq, const float* __restrict__ Wk,
                        const float* __restrict__ Wv, unsigned short* __restrict__ Wf)
{
    int idx = blockIdx.x * 256 + threadIdx.x;   // < 196608
    int j = idx & 7, lane = (idx >> 3) & 63, nf = (idx >> 9) & 3,
        kstep = (idx >> 11) & 31, m = idx >> 16;
    int k = kstep * 32 + 8 * (lane >> 4) + j;
    int n = nf * 16 + (lane & 15);
    const float* W = (m == 0) ? Wq : (m == 1) ? Wk : Wv;
    Wf[idx] = f2bf(W[k * 64 + n]);
}

// ---------- QKV projection: zero LDS, zero barriers ----------
// 512 blocks x 256 thr. Block = 32 token rows; waves: strip(2) x chalf(2).
// x frags loaded direct from global (depth-4 prefetch); W frags from Wf.
// Outputs written in MFMA-fragment order (Qf/Kf/Vf) so attn loads coalesce.
__global__ __launch_bounds__(256, 2)
void proj_qkv(const float* __restrict__ x, const unsigned short* __restrict__ Wf,
              const float* __restrict__ bq, const float* __restrict__ bk,
              const float* __restrict__ bv,
              unsigned short* __restrict__ Qf, unsigned short* __restrict__ Kf,
              unsigned short* __restrict__ Vf)
{
    const int tid = threadIdx.x;
    const int w = tid >> 6, l = tid & 63;
    const int strip = w & 1, chalf = w >> 1;
    const int row0 = blockIdx.x * 32;
    const int row = row0 + strip * 16 + (l & 15);
    const float* xp = x + (size_t)row * D_MODEL + 8 * (l >> 4);

    f4v acc[6];
#pragma unroll
    for (int i = 0; i < 6; ++i) acc[i] = (f4v)0.f;

    f4v xv[4][2];
#pragma unroll
    for (int i = 0; i < 4; ++i) {
        xv[i][0] = *(const f4v*)(xp + 32 * i);
        xv[i][1] = *(const f4v*)(xp + 32 * i + 4);
    }

    for (int ko = 0; ko < 32; ko += 4) {
#pragma unroll
        for (int ki = 0; ki < 4; ++ki) {
            const int ks = ko + ki;
            f4v a = xv[ki][0], b = xv[ki][1];
            if (ks + 4 < 32) {   // rolling depth-4 prefetch (static slot index)
                xv[ki][0] = *(const f4v*)(xp + 32 * (ks + 4));
                xv[ki][1] = *(const f4v*)(xp + 32 * (ks + 4) + 4);
            }
            // hi/lo bf16 split (residual is exact regardless of cvt rounding)
            unsigned p0 = cvtpk(a[0], a[1]), p1 = cvtpk(a[2], a[3]);
            unsigned p2 = cvtpk(b[0], b[1]), p3 = cvtpk(b[2], b[3]);
            u32x4 hw = {p0, p1, p2, p3};
            bf16x8 hi = __builtin_bit_cast(bf16x8, hw);
            float e0 = a[0] - asf(p0 << 16), e1 = a[1] - asf(p0 & 0xFFFF0000u);
            float e2 = a[2] - asf(p1 << 16), e3 = a[3] - asf(p1 & 0xFFFF0000u);
            float e4 = b[0] - asf(p2 << 16), e5 = b[1] - asf(p2 & 0xFFFF0000u);
            float e6 = b[2] - asf(p3 << 16), e7 = b[3] - asf(p3 & 0xFFFF0000u);
            unsigned q0 = cvtpk(e0, e1), q1 = cvtpk(e2, e3);
            unsigned q2 = cvtpk(e4, e5), q3 = cvtpk(e6, e7);
            u32x4 lw = {q0, q1, q2, q3};
            bf16x8 lo = __builtin_bit_cast(bf16x8, lw);
#pragma unroll
            for (int f = 0; f < 6; ++f) {
                const int mc = chalf * 6 + f;
                const unsigned short* wp =
                    Wf + ((((mc >> 2) * 32 + ks) * 4 + (mc & 3)) << 9) + l * 8;
                bf16x8 bw = ld8(wp);
                acc[f] = mfma16(hi, bw, acc[f]);
                acc[f] = mfma16(lo, bw, acc[f]);
            }
        }
    }

    const float* bias[3] = {bq, bk, bv};
    const int rowb = row0 + strip * 16 + 4 * (l >> 4);
#pragma unroll
    for (int f = 0; f < 6; ++f) {
        const int mc = chalf * 6 + f;
        const int m = mc >> 2, nf = mc & 3;
        const int d = nf * 16 + (l & 15);
        const float bb = bias[m][d];
        const int b = rowb >> 12, tok0 = rowb & 4095;
        if (m == 0) {
            const int qtile = tok0 >> 5;
            const int ksq = d >> 4, hq = (d >> 3) & 1, jq = d & 7;
#pragma unroll
            for (int r4 = 0; r4 < 4; ++r4) {
                int cq = (tok0 & 31) + r4;
                Qf[(((size_t)(b * 128 + qtile) * 4 + ksq) << 9) + (32 * hq + cq) * 8 + jq] =
                    f2bf((acc[f][r4] + bb) * QSCALE);
            }
        } else if (m == 1) {
            const int t = tok0 >> 6, tb = (tok0 >> 5) & 1;
            const int ksk = d >> 4, hk = (d >> 3) & 1, jk = d & 7;
#pragma unroll
            for (int r4 = 0; r4 < 4; ++r4) {
                int ck = (tok0 & 31) + r4;
                Kf[(((size_t)((b * 64 + t) * 8 + tb * 4 + ksk)) << 9) + (32 * hk + ck) * 8 + jk] =
                    f2bf(acc[f][r4] + bb);
            }
        } else {
            // Vf element (lane', j) = V[kv = t*64 + 16ku + 8hv + j][dv = 32td + c']
            const int t = tok0 >> 6, ku = (tok0 >> 4) & 3, hv = (tok0 >> 3) & 1, jv = tok0 & 7;
            const int cv = d & 31, td = d >> 5;
            u16x4 pk;
#pragma unroll
            for (int r4 = 0; r4 < 4; ++r4) pk[r4] = f2bf(acc[f][r4] + bb);
            *(u16x4*)(Vf + (((size_t)((b * 64 + t) * 8 + td * 4 + ku)) << 9) +
                      (32 * hv + cv) * 8 + jv) = pk;
        }
    }
}

// ---------- flash attention ----------
// 256 blocks (4 batch x 64 q-tile PAIRS {pr, 127-pr}: constant work) x 8 waves.
// batch = bid&3 -> each XCD sees one batch -> K/V L2-resident.
// Wave g handles kv tiles t = g, g+8, ... for BOTH q-tiles -> balanced per wave.
// All operand loads are 1KB coalesced ld8 from fragment-order Qf/Kf/Vf.
struct TState { float m, l; f16v o0, o1; };

__device__ __forceinline__ void run_tile(const unsigned short* __restrict__ Qf,
                                         const unsigned short* __restrict__ Kf,
                                         const unsigned short* __restrict__ Vf,
                                         int batch, int qt, int g8, int l, int h, int c,
                                         TState& st)
{
    const int NT = (qt >> 1) + 1;
    st.m = -1e30f; st.l = 0.f; st.o0 = (f16v)0.f; st.o1 = (f16v)0.f;

    bf16x8 qf[4];
    const unsigned short* qp = Qf + (((size_t)(batch * 128 + qt) * 4) << 9) + l * 8;
#pragma unroll
    for (int ks = 0; ks < 4; ++ks) qf[ks] = ld8(qp + (ks << 9));

    if (g8 >= NT) return;

    auto kload = [&](bf16x8(&kr)[2][4], int t_) {
        const unsigned short* p = Kf + (((size_t)(batch * 64 + t_) * 8) << 9) + l * 8;
#pragma unroll
        for (int tb = 0; tb < 2; ++tb)
#pragma unroll
            for (int ks = 0; ks < 4; ++ks)
                kr[tb][ks] = ld8(p + ((tb * 4 + ks) << 9));
    };

    auto body = [&](bf16x8(&kr)[2][4], bf16x8(&kn)[2][4], int t_) {
        bf16x8 vr[2][4];
        {
            const unsigned short* p = Vf + (((size_t)(batch * 64 + t_) * 8) << 9) + l * 8;
#pragma unroll
            for (int td = 0; td < 2; ++td)
#pragma unroll
                for (int ku = 0; ku < 4; ++ku)
                    vr[td][ku] = ld8(p + ((td * 4 + ku) << 9));
        }
        // S^T = K Q^T
        f16v sacc[2];
        sacc[0] = (f16v)0.f; sacc[1] = (f16v)0.f;
#pragma unroll
        for (int ks = 0; ks < 4; ++ks) {
            sacc[0] = mfma32(kr[0][ks], qf[ks], sacc[0]);
            sacc[1] = mfma32(kr[1][ks], qf[ks], sacc[1]);
        }
        int tn = t_ + 8; if (tn > NT - 1) tn = NT - 1;
        kload(kn, tn);
        if (t_ == NT - 1) {   // causal mask on diagonal tile
            const int off = qt * QB - t_ * KVB;
#pragma unroll
            for (int tb = 0; tb < 2; ++tb)
#pragma unroll
                for (int r = 0; r < 16; ++r) {
                    int mv = 32 * tb + (r & 3) + 8 * (r >> 2) + 4 * h - off;
                    if (mv > c) sacc[tb][r] = -1e30f;
                }
        }
        // online softmax (exp2 domain)
        float pm = -1e30f;
#pragma unroll
        for (int tb = 0; tb < 2; ++tb)
#pragma unroll
            for (int r = 0; r < 16; ++r) pm = fmaxf(pm, sacc[tb][r]);
        pm = fmaxf(pm, __shfl_xor(pm, 32));
        const float mnew = fmaxf(st.m, pm);
        const float sc = exp2f(st.m - mnew);
        st.m = mnew;
        float rs = 0.f;
        float p[2][16];
#pragma unroll
        for (int tb = 0; tb < 2; ++tb)
#pragma unroll
            for (int r = 0; r < 16; ++r) {
                float e = exp2f(sacc[tb][r] - mnew);
                p[tb][r] = e; rs += e;
            }
        rs += __shfl_xor(rs, 32);
        st.l = st.l * sc + rs;
#pragma unroll
        for (int r = 0; r < 16; ++r) { st.o0[r] *= sc; st.o1[r] *= sc; }
        // P (C-layout) -> frag via cvt_pk + permlane32_swap
        bf16x8 pa[4];
#pragma unroll
        for (int tb = 0; tb < 2; ++tb) {
            unsigned wp[8];
#pragma unroll
            for (int i = 0; i < 8; ++i) wp[i] = cvtpk(p[tb][2 * i], p[tb][2 * i + 1]);
            pswap(wp[0], wp[2]); pswap(wp[1], wp[3]);
            pswap(wp[4], wp[6]); pswap(wp[5], wp[7]);
            u32x4 f0 = {wp[0], wp[1], wp[2], wp[3]};
            u32x4 f1 = {wp[4], wp[5], wp[6], wp[7]};
            pa[2 * tb]     = __builtin_bit_cast(bf16x8, f0);
            pa[2 * tb + 1] = __builtin_bit_cast(bf16x8, f1);
        }
        // O^T += V^T P^T (C cols are q = c -> lane-local rescale is exact)
#pragma unroll
        for (int ku = 0; ku < 4; ++ku) {
            st.o0 = mfma32(vr[0][ku], pa[ku], st.o0);
            st.o1 = mfma32(vr[1][ku], pa[ku], st.o1);
        }
    };

    bf16x8 kA[2][4], kB[2][4];
    int t = g8;
    kload(kA, t);
    for (;;) {
        body(kA, kB, t);
        t += 8; if (t >= NT) break;
        body(kB, kA, t);
        t += 8; if (t >= NT) break;
    }
}

__global__ __launch_bounds__(512, 2)
void attn(const unsigned short* __restrict__ Qf, const unsigned short* __restrict__ Kf,
          const unsigned short* __restrict__ Vf, float* __restrict__ Yg)
{
    __shared__ float Osm[8][QB][33];
    __shared__ float Msm[2][8][QB];
    __shared__ float Lsm[2][8][QB];

    const int tid = threadIdx.x;
    const int g8 = tid >> 6, l = tid & 63, h = l >> 5, c = l & 31;
    const int batch = blockIdx.x & 3;
    const int pr = blockIdx.x >> 2;
    const int qtA = pr, qtB = 127 - pr;

    TState sB, sA;
    run_tile(Qf, Kf, Vf, batch, qtB, g8, l, h, c, sB);
    run_tile(Qf, Kf, Vf, batch, qtA, g8, l, h, c, sA);

    if (h == 0) {
        Msm[0][g8][c] = sA.m; Lsm[0][g8][c] = sA.l;
        Msm[1][g8][c] = sB.m; Lsm[1][g8][c] = sB.l;
    }

    auto write_partial = [&](const f16v& o) {
#pragma unroll
        for (int r = 0; r < 16; ++r) {
            int dd = (r & 3) + 8 * (r >> 2) + 4 * h;
            Osm[g8][c][dd] = o[r];
        }
    };
    auto merge_phase = [&](int tile, int dhalf, int qt_) {
        const int q = tid >> 4, d2 = (tid & 15) * 2;
        float mm = -1e30f;
#pragma unroll
        for (int gg = 0; gg < 8; ++gg) mm = fmaxf(mm, Msm[tile][gg][q]);
        float L = 0.f, o0 = 0.f, o1 = 0.f;
#pragma unroll
        for (int gg = 0; gg < 8; ++gg) {
            float a = exp2f(Msm[tile][gg][q] - mm);
            L += a * Lsm[tile][gg][q];
            o0 += a * Osm[gg][q][d2];
            o1 += a * Osm[gg][q][d2 + 1];
        }
        float inv = 1.f / L;
        float* yp = Yg + ((size_t)batch * TSEQ + (size_t)qt_ * QB + q) * HDIM + dhalf * 32 + d2;
        yp[0] = o0 * inv; yp[1] = o1 * inv;
    };

    write_partial(sA.o0);
    __syncthreads();
    merge_phase(0, 0, qtA);
    __syncthreads();
    write_partial(sA.o1);
    __syncthreads();
    merge_phase(0, 1, qtA);
    __syncthreads();
    write_partial(sB.o0);
    __syncthreads();
    merge_phase(1, 0, qtB);
    __syncthreads();
    write_partial(sB.o1);
    __syncthreads();
    merge_phase(1, 1, qtB);
}

extern "C" void kernel_launch(void* const* d_in, const int* in_sizes, int n_in,
                              void* d_out, int out_size, void* d_ws, size_t ws_size,
                              hipStream_t stream)
{
    const float* x  = (const float*)d_in[0];
    const float* Wq = (const float*)d_in[1];
    const float* bq = (const float*)d_in[2];
    const float* Wk = (const float*)d_in[3];
    const float* bk = (const float*)d_in[4];
    const float* Wv = (const float*)d_in[5];
    const float* bv = (const float*)d_in[6];
    float* y = (float*)d_out;

    unsigned short* Qb = (unsigned short*)d_ws;          // 4*128*4*512 = 1M bf16
    unsigned short* Kb = Qb + (size_t)1048576;           // 4*64*8*512  = 1M bf16
    unsigned short* Vb = Kb + (size_t)1048576;           // 1M bf16
    unsigned short* Wf = Vb + (size_t)1048576;           // 196608 bf16

    prep_wf<<<768, 256, 0, stream>>>(Wq, Wk, Wv, Wf);
    proj_qkv<<<512, 256, 0, stream>>>(x, Wf, bq, bk, bv, Qb, Kb, Vb);
    attn<<<256, 512, 0, stream>>>(Qb, Kb, Vb, y);
}

// Round 5
// 56.763 us; speedup vs baseline: 1.6759x; 1.6759x over previous
//
#include <hip/hip_runtime.h>
#include <hip/hip_bf16.h>

typedef __attribute__((ext_vector_type(4))) float f4v;
typedef __attribute__((ext_vector_type(16))) float f16v;
typedef __attribute__((ext_vector_type(4))) unsigned short u16x4;
typedef __attribute__((ext_vector_type(8))) unsigned short u16x8;
typedef __attribute__((ext_vector_type(2))) unsigned int u32x2;
typedef __attribute__((ext_vector_type(4))) unsigned int u32x4;
typedef __attribute__((ext_vector_type(8))) __bf16 bf16x8;

#define D_MODEL 1024
#define HDIM 64
#define TSEQ 4096
#define QB 32
#define KVB 64
// 1/sqrt(HDIM) * log2(e), folded into Q at projection
#define QSCALE 0.18033688011112042f

__device__ __forceinline__ unsigned short f2bf(float f) {
    union { float f; unsigned u; } v; v.f = f;
    unsigned r = v.u + 0x7FFFu + ((v.u >> 16) & 1u);
    return (unsigned short)(r >> 16);
}
__device__ __forceinline__ float asf(unsigned u) {
    union { unsigned u; float f; } v; v.u = u; return v.f;
}
__device__ __forceinline__ bf16x8 ld8(const unsigned short* p) {
    return __builtin_bit_cast(bf16x8, *(const u16x8*)p);
}
__device__ __forceinline__ f4v mfma16(bf16x8 a, bf16x8 b, f4v c) {
    return __builtin_amdgcn_mfma_f32_16x16x32_bf16(a, b, c, 0, 0, 0);
}
__device__ __forceinline__ f16v mfma32(bf16x8 a, bf16x8 b, f16v c) {
    return __builtin_amdgcn_mfma_f32_32x32x16_bf16(a, b, c, 0, 0, 0);
}
__device__ __forceinline__ unsigned cvtpk(float a, float b) {
    unsigned r;
    asm("v_cvt_pk_bf16_f32 %0, %1, %2" : "=v"(r) : "v"(a), "v"(b));
    return r;
}
__device__ __forceinline__ void pswap(unsigned& a, unsigned& b) {
    asm("v_permlane32_swap_b32 %0, %1" : "+v"(a), "+v"(b));
}

// ---------- W -> fragment-order bf16: Wf[m][kstep(32)][nf(4)][lane(64)][8] ----------
// element = W[m][k = kstep*32 + 8*(lane>>4) + j][n = nf*16 + (lane&15)]
__global__ void prep_wf(const float* __restrict__ Wq, const float* __restrict__ Wk,
                        const float* __restrict__ Wv, unsigned short* __restrict__ Wf)
{
    int idx = blockIdx.x * 256 + threadIdx.x;   // < 196608
    int j = idx & 7, lane = (idx >> 3) & 63, nf = (idx >> 9) & 3,
        kstep = (idx >> 11) & 31, m = idx >> 16;
    int k = kstep * 32 + 8 * (lane >> 4) + j;
    int n = nf * 16 + (lane & 15);
    const float* W = (m == 0) ? Wq : (m == 1) ? Wk : Wv;
    Wf[idx] = f2bf(W[k * 64 + n]);
}

// ---------- QKV projection ----------
// 512 blocks x 256 thr, BM=32 token rows, BK=64.
// x staged COALESCED -> LDS as hi/lo bf16 (one conversion, shared by waves).
// W frags read directly from global Wf (frag-order, L2-resident, 1KB/instr).
// Waves col-split: wave w owns col-frags 3w..3w+2 over both 16-row strips.
// Outputs written in MFMA-fragment order (Qf/Kf/Vf) so attn loads coalesce.
__global__ __launch_bounds__(256, 2)
void proj_qkv(const float* __restrict__ x, const unsigned short* __restrict__ Wf,
              const float* __restrict__ bq, const float* __restrict__ bk,
              const float* __restrict__ bv,
              unsigned short* __restrict__ Qf, unsigned short* __restrict__ Kf,
              unsigned short* __restrict__ Vf)
{
    __shared__ unsigned short xhi[32][72];
    __shared__ unsigned short xlo[32][72];

    const int tid = threadIdx.x;
    const int w = tid >> 6, l = tid & 63;
    const int row0 = blockIdx.x * 32;

    f4v acc[2][3];
#pragma unroll
    for (int s = 0; s < 2; ++s)
#pragma unroll
        for (int f = 0; f < 3; ++f) acc[s][f] = (f4v)0.f;

    for (int k0 = 0; k0 < D_MODEL; k0 += 64) {
        __syncthreads();
        // stage x[32][k0..k0+64): id -> (row = id>>4, 16B chunk c4 = id&15)
#pragma unroll
        for (int io = 0; io < 2; ++io) {
            int id = io * 256 + tid;
            int r = id >> 4, c4 = id & 15;
            f4v a = *(const f4v*)(x + (size_t)(row0 + r) * D_MODEL + k0 + c4 * 4);
            unsigned p0 = cvtpk(a[0], a[1]), p1 = cvtpk(a[2], a[3]);
            u32x2 hw = {p0, p1};
            *(u16x4*)&xhi[r][c4 * 4] = __builtin_bit_cast(u16x4, hw);
            // residual is exact regardless of cvt rounding mode
            float e0 = a[0] - asf(p0 << 16), e1 = a[1] - asf(p0 & 0xFFFF0000u);
            float e2 = a[2] - asf(p1 << 16), e3 = a[3] - asf(p1 & 0xFFFF0000u);
            unsigned q0 = cvtpk(e0, e1), q1 = cvtpk(e2, e3);
            u32x2 lw = {q0, q1};
            *(u16x4*)&xlo[r][c4 * 4] = __builtin_bit_cast(u16x4, lw);
        }
        __syncthreads();
#pragma unroll
        for (int ks = 0; ks < 2; ++ks) {
            const int kglob = (k0 >> 5) + ks;
            bf16x8 bw[3];
#pragma unroll
            for (int f = 0; f < 3; ++f) {
                const int cf = w * 3 + f;
                bw[f] = ld8(Wf + ((((cf >> 2) * 32 + kglob) * 4 + (cf & 3)) << 9) + l * 8);
            }
#pragma unroll
            for (int s = 0; s < 2; ++s) {
                bf16x8 xh = ld8(&xhi[s * 16 + (l & 15)][ks * 32 + 8 * (l >> 4)]);
                bf16x8 xl = ld8(&xlo[s * 16 + (l & 15)][ks * 32 + 8 * (l >> 4)]);
#pragma unroll
                for (int f = 0; f < 3; ++f) {
                    acc[s][f] = mfma16(xh, bw[f], acc[s][f]);
                    acc[s][f] = mfma16(xl, bw[f], acc[s][f]);
                }
            }
        }
    }

    const float* bias[3] = {bq, bk, bv};
#pragma unroll
    for (int s = 0; s < 2; ++s) {
        const int rowb = row0 + s * 16 + 4 * (l >> 4);
        const int b = rowb >> 12, tok0 = rowb & 4095;
#pragma unroll
        for (int f = 0; f < 3; ++f) {
            const int cf = w * 3 + f;
            const int m = cf >> 2, nf = cf & 3;
            const int d = nf * 16 + (l & 15);
            const float bb = bias[m][d];
            if (m == 0) {
                const int qtile = tok0 >> 5;
                const int ksq = d >> 4, hq = (d >> 3) & 1, jq = d & 7;
#pragma unroll
                for (int r4 = 0; r4 < 4; ++r4) {
                    int cq = (tok0 & 31) + r4;
                    Qf[(((size_t)(b * 128 + qtile) * 4 + ksq) << 9) + (32 * hq + cq) * 8 + jq] =
                        f2bf((acc[s][f][r4] + bb) * QSCALE);
                }
            } else if (m == 1) {
                const int t = tok0 >> 6, tb = (tok0 >> 5) & 1;
                const int ksk = d >> 4, hk = (d >> 3) & 1, jk = d & 7;
#pragma unroll
                for (int r4 = 0; r4 < 4; ++r4) {
                    int ck = (tok0 & 31) + r4;
                    Kf[(((size_t)((b * 64 + t) * 8 + tb * 4 + ksk)) << 9) + (32 * hk + ck) * 8 + jk] =
                        f2bf(acc[s][f][r4] + bb);
                }
            } else {
                // Vf element (lane', j) = V[kv = t*64 + 16ku + 8hv + j][dv = 32td + c']
                const int t = tok0 >> 6, ku = (tok0 >> 4) & 3, hv = (tok0 >> 3) & 1, jv = tok0 & 7;
                const int cv = d & 31, td = d >> 5;
                u16x4 pk;
#pragma unroll
                for (int r4 = 0; r4 < 4; ++r4) pk[r4] = f2bf(acc[s][f][r4] + bb);
                *(u16x4*)(Vf + (((size_t)((b * 64 + t) * 8 + td * 4 + ku)) << 9) +
                          (32 * hv + cv) * 8 + jv) = pk;
            }
        }
    }
}

// ---------- flash attention ----------
// 256 blocks (4 batch x 64 q-tile PAIRS {pr, 127-pr}: constant work) x 8 waves.
// batch = bid&3 -> each XCD sees one batch -> K/V L2-resident.
// Wave g handles kv tiles t = g, g+8, ... for BOTH q-tiles -> balanced per wave.
// All operand loads are 1KB coalesced ld8 from fragment-order Qf/Kf/Vf.
struct TState { float m, l; f16v o0, o1; };

__device__ __forceinline__ void run_tile(const unsigned short* __restrict__ Qf,
                                         const unsigned short* __restrict__ Kf,
                                         const unsigned short* __restrict__ Vf,
                                         int batch, int qt, int g8, int l, int h, int c,
                                         TState& st)
{
    const int NT = (qt >> 1) + 1;
    st.m = -1e30f; st.l = 0.f; st.o0 = (f16v)0.f; st.o1 = (f16v)0.f;

    bf16x8 qf[4];
    const unsigned short* qp = Qf + (((size_t)(batch * 128 + qt) * 4) << 9) + l * 8;
#pragma unroll
    for (int ks = 0; ks < 4; ++ks) qf[ks] = ld8(qp + (ks << 9));

    if (g8 >= NT) return;

    auto kload = [&](bf16x8(&kr)[2][4], int t_) {
        const unsigned short* p = Kf + (((size_t)(batch * 64 + t_) * 8) << 9) + l * 8;
#pragma unroll
        for (int tb = 0; tb < 2; ++tb)
#pragma unroll
            for (int ks = 0; ks < 4; ++ks)
                kr[tb][ks] = ld8(p + ((tb * 4 + ks) << 9));
    };

    auto body = [&](bf16x8(&kr)[2][4], bf16x8(&kn)[2][4], int t_) {
        bf16x8 vr[2][4];
        {
            const unsigned short* p = Vf + (((size_t)(batch * 64 + t_) * 8) << 9) + l * 8;
#pragma unroll
            for (int td = 0; td < 2; ++td)
#pragma unroll
                for (int ku = 0; ku < 4; ++ku)
                    vr[td][ku] = ld8(p + ((td * 4 + ku) << 9));
        }
        // S^T = K Q^T
        f16v sacc[2];
        sacc[0] = (f16v)0.f; sacc[1] = (f16v)0.f;
#pragma unroll
        for (int ks = 0; ks < 4; ++ks) {
            sacc[0] = mfma32(kr[0][ks], qf[ks], sacc[0]);
            sacc[1] = mfma32(kr[1][ks], qf[ks], sacc[1]);
        }
        int tn = t_ + 8; if (tn > NT - 1) tn = NT - 1;
        kload(kn, tn);
        if (t_ == NT - 1) {   // causal mask on diagonal tile
            const int off = qt * QB - t_ * KVB;
#pragma unroll
            for (int tb = 0; tb < 2; ++tb)
#pragma unroll
                for (int r = 0; r < 16; ++r) {
                    int mv = 32 * tb + (r & 3) + 8 * (r >> 2) + 4 * h - off;
                    if (mv > c) sacc[tb][r] = -1e30f;
                }
        }
        // online softmax (exp2 domain)
        float pm = -1e30f;
#pragma unroll
        for (int tb = 0; tb < 2; ++tb)
#pragma unroll
            for (int r = 0; r < 16; ++r) pm = fmaxf(pm, sacc[tb][r]);
        pm = fmaxf(pm, __shfl_xor(pm, 32));
        const float mnew = fmaxf(st.m, pm);
        const float sc = exp2f(st.m - mnew);
        st.m = mnew;
        float rs = 0.f;
        float p[2][16];
#pragma unroll
        for (int tb = 0; tb < 2; ++tb)
#pragma unroll
            for (int r = 0; r < 16; ++r) {
                float e = exp2f(sacc[tb][r] - mnew);
                p[tb][r] = e; rs += e;
            }
        rs += __shfl_xor(rs, 32);
        st.l = st.l * sc + rs;
#pragma unroll
        for (int r = 0; r < 16; ++r) { st.o0[r] *= sc; st.o1[r] *= sc; }
        // P (C-layout) -> frag via cvt_pk + permlane32_swap
        bf16x8 pa[4];
#pragma unroll
        for (int tb = 0; tb < 2; ++tb) {
            unsigned wp[8];
#pragma unroll
            for (int i = 0; i < 8; ++i) wp[i] = cvtpk(p[tb][2 * i], p[tb][2 * i + 1]);
            pswap(wp[0], wp[2]); pswap(wp[1], wp[3]);
            pswap(wp[4], wp[6]); pswap(wp[5], wp[7]);
            u32x4 f0 = {wp[0], wp[1], wp[2], wp[3]};
            u32x4 f1 = {wp[4], wp[5], wp[6], wp[7]};
            pa[2 * tb]     = __builtin_bit_cast(bf16x8, f0);
            pa[2 * tb + 1] = __builtin_bit_cast(bf16x8, f1);
        }
        // O^T += V^T P^T (C cols are q = c -> lane-local rescale is exact)
#pragma unroll
        for (int ku = 0; ku < 4; ++ku) {
            st.o0 = mfma32(vr[0][ku], pa[ku], st.o0);
            st.o1 = mfma32(vr[1][ku], pa[ku], st.o1);
        }
    };

    bf16x8 kA[2][4], kB[2][4];
    int t = g8;
    kload(kA, t);
    for (;;) {
        body(kA, kB, t);
        t += 8; if (t >= NT) break;
        body(kB, kA, t);
        t += 8; if (t >= NT) break;
    }
}

__global__ __launch_bounds__(512, 2)
void attn(const unsigned short* __restrict__ Qf, const unsigned short* __restrict__ Kf,
          const unsigned short* __restrict__ Vf, float* __restrict__ Yg)
{
    __shared__ float Osm[8][QB][33];
    __shared__ float Msm[2][8][QB];
    __shared__ float Lsm[2][8][QB];

    const int tid = threadIdx.x;
    const int g8 = tid >> 6, l = tid & 63, h = l >> 5, c = l & 31;
    const int batch = blockIdx.x & 3;
    const int pr = blockIdx.x >> 2;
    const int qtA = pr, qtB = 127 - pr;

    TState sB, sA;
    run_tile(Qf, Kf, Vf, batch, qtB, g8, l, h, c, sB);
    run_tile(Qf, Kf, Vf, batch, qtA, g8, l, h, c, sA);

    if (h == 0) {
        Msm[0][g8][c] = sA.m; Lsm[0][g8][c] = sA.l;
        Msm[1][g8][c] = sB.m; Lsm[1][g8][c] = sB.l;
    }

    auto write_partial = [&](const f16v& o) {
#pragma unroll
        for (int r = 0; r < 16; ++r) {
            int dd = (r & 3) + 8 * (r >> 2) + 4 * h;
            Osm[g8][c][dd] = o[r];
        }
    };
    auto merge_phase = [&](int tile, int dhalf, int qt_) {
        const int q = tid >> 4, d2 = (tid & 15) * 2;
        float mm = -1e30f;
#pragma unroll
        for (int gg = 0; gg < 8; ++gg) mm = fmaxf(mm, Msm[tile][gg][q]);
        float L = 0.f, o0 = 0.f, o1 = 0.f;
#pragma unroll
        for (int gg = 0; gg < 8; ++gg) {
            float a = exp2f(Msm[tile][gg][q] - mm);
            L += a * Lsm[tile][gg][q];
            o0 += a * Osm[gg][q][d2];
            o1 += a * Osm[gg][q][d2 + 1];
        }
        float inv = 1.f / L;
        float* yp = Yg + ((size_t)batch * TSEQ + (size_t)qt_ * QB + q) * HDIM + dhalf * 32 + d2;
        yp[0] = o0 * inv; yp[1] = o1 * inv;
    };

    write_partial(sA.o0);
    __syncthreads();
    merge_phase(0, 0, qtA);
    __syncthreads();
    write_partial(sA.o1);
    __syncthreads();
    merge_phase(0, 1, qtA);
    __syncthreads();
    write_partial(sB.o0);
    __syncthreads();
    merge_phase(1, 0, qtB);
    __syncthreads();
    write_partial(sB.o1);
    __syncthreads();
    merge_phase(1, 1, qtB);
}

extern "C" void kernel_launch(void* const* d_in, const int* in_sizes, int n_in,
                              void* d_out, int out_size, void* d_ws, size_t ws_size,
                              hipStream_t stream)
{
    const float* x  = (const float*)d_in[0];
    const float* Wq = (const float*)d_in[1];
    const float* bq = (const float*)d_in[2];
    const float* Wk = (const float*)d_in[3];
    const float* bk = (const float*)d_in[4];
    const float* Wv = (const float*)d_in[5];
    const float* bv = (const float*)d_in[6];
    float* y = (float*)d_out;

    unsigned short* Qb = (unsigned short*)d_ws;          // 4*128*4*512 = 1M bf16
    unsigned short* Kb = Qb + (size_t)1048576;           // 4*64*8*512  = 1M bf16
    unsigned short* Vb = Kb + (size_t)1048576;           // 1M bf16
    unsigned short* Wf = Vb + (size_t)1048576;           // 196608 bf16

    prep_wf<<<768, 256, 0, stream>>>(Wq, Wk, Wv, Wf);
    proj_qkv<<<512, 256, 0, stream>>>(x, Wf, bq, bk, bv, Qb, Kb, Vb);
    attn<<<256, 512, 0, stream>>>(Qb, Kb, Vb, y);
}

// Round 6
// 51.799 us; speedup vs baseline: 1.8366x; 1.0958x over previous
//
#include <hip/hip_runtime.h>
#include <hip/hip_bf16.h>

typedef __attribute__((ext_vector_type(4))) float f4v;
typedef __attribute__((ext_vector_type(16))) float f16v;
typedef __attribute__((ext_vector_type(4))) unsigned short u16x4;
typedef __attribute__((ext_vector_type(8))) unsigned short u16x8;
typedef __attribute__((ext_vector_type(2))) unsigned int u32x2;
typedef __attribute__((ext_vector_type(4))) unsigned int u32x4;
typedef __attribute__((ext_vector_type(8))) __bf16 bf16x8;

#define D_MODEL 1024
#define HDIM 64
#define TSEQ 4096
#define QB 32
#define KVB 64
// 1/sqrt(HDIM) * log2(e), folded into Q at projection
#define QSCALE 0.18033688011112042f

__device__ __forceinline__ unsigned short f2bf(float f) {
    union { float f; unsigned u; } v; v.f = f;
    unsigned r = v.u + 0x7FFFu + ((v.u >> 16) & 1u);
    return (unsigned short)(r >> 16);
}
__device__ __forceinline__ float asf(unsigned u) {
    union { unsigned u; float f; } v; v.u = u; return v.f;
}
__device__ __forceinline__ bf16x8 ld8(const unsigned short* p) {
    return __builtin_bit_cast(bf16x8, *(const u16x8*)p);
}
__device__ __forceinline__ f4v mfma16(bf16x8 a, bf16x8 b, f4v c) {
    return __builtin_amdgcn_mfma_f32_16x16x32_bf16(a, b, c, 0, 0, 0);
}
__device__ __forceinline__ f16v mfma32(bf16x8 a, bf16x8 b, f16v c) {
    return __builtin_amdgcn_mfma_f32_32x32x16_bf16(a, b, c, 0, 0, 0);
}
__device__ __forceinline__ unsigned cvtpk(float a, float b) {
    unsigned r;
    asm("v_cvt_pk_bf16_f32 %0, %1, %2" : "=v"(r) : "v"(a), "v"(b));
    return r;
}
__device__ __forceinline__ void pswap(unsigned& a, unsigned& b) {
    asm("v_permlane32_swap_b32 %0, %1" : "+v"(a), "+v"(b));
}

// ---------- W -> fragment-order bf16: Wf[m][kstep(32)][nf(4)][lane(64)][8] ----------
// element = W[m][k = kstep*32 + 8*(lane>>4) + j][n = nf*16 + (lane&15)]
__global__ void prep_wf(const float* __restrict__ Wq, const float* __restrict__ Wk,
                        const float* __restrict__ Wv, unsigned short* __restrict__ Wf)
{
    int idx = blockIdx.x * 256 + threadIdx.x;   // < 196608
    int j = idx & 7, lane = (idx >> 3) & 63, nf = (idx >> 9) & 3,
        kstep = (idx >> 11) & 31, m = idx >> 16;
    int k = kstep * 32 + 8 * (lane >> 4) + j;
    int n = nf * 16 + (lane & 15);
    const float* W = (m == 0) ? Wq : (m == 1) ? Wk : Wv;
    Wf[idx] = f2bf(W[k * 64 + n]);
}

// ---------- QKV projection ----------
// 1024 blocks x 256 thr (4 blocks/CU, 16 waves/CU), BM=16 rows, BK=64.
// One-barrier-per-iter pipeline: cvt+write LDS buf[t&1] -> issue x(t+1) load
// -> barrier -> compute(t). buf[t&1] rewrite at t+2 is fenced by barrier(t+1),
// which each wave reaches only after its compute(t) -> race-free.
// W frags straight from global Wf (L2-resident); all 4 waves share the strip,
// col-split 3 frags each. Outputs in MFMA-fragment order for attn.
__global__ __launch_bounds__(256, 4)
void proj_qkv(const float* __restrict__ x, const unsigned short* __restrict__ Wf,
              const float* __restrict__ bq, const float* __restrict__ bk,
              const float* __restrict__ bv,
              unsigned short* __restrict__ Qf, unsigned short* __restrict__ Kf,
              unsigned short* __restrict__ Vf)
{
    __shared__ unsigned short xhi[2][16][72];
    __shared__ unsigned short xlo[2][16][72];

    const int tid = threadIdx.x;
    const int w = tid >> 6, l = tid & 63;
    const int row0 = blockIdx.x * 16;
    const int sr = tid >> 4, sc = tid & 15;   // staging: row, 8B chunk
    const float* xp = x + (size_t)(row0 + sr) * D_MODEL + sc * 4;

    f4v acc[3];
#pragma unroll
    for (int f = 0; f < 3; ++f) acc[f] = (f4v)0.f;

    f4v xv = *(const f4v*)xp;

#pragma unroll
    for (int t = 0; t < 16; ++t) {
        // convert tile t (regs) -> LDS buf[t&1]; residual split is exact
        unsigned p0 = cvtpk(xv[0], xv[1]), p1 = cvtpk(xv[2], xv[3]);
        u32x2 hw = {p0, p1};
        *(u16x4*)&xhi[t & 1][sr][sc * 4] = __builtin_bit_cast(u16x4, hw);
        float e0 = xv[0] - asf(p0 << 16), e1 = xv[1] - asf(p0 & 0xFFFF0000u);
        float e2 = xv[2] - asf(p1 << 16), e3 = xv[3] - asf(p1 & 0xFFFF0000u);
        unsigned q0 = cvtpk(e0, e1), q1 = cvtpk(e2, e3);
        u32x2 lw = {q0, q1};
        *(u16x4*)&xlo[t & 1][sr][sc * 4] = __builtin_bit_cast(u16x4, lw);
        if (t < 15) xv = *(const f4v*)(xp + 64 * (t + 1));   // prefetch t+1
        __syncthreads();
#pragma unroll
        for (int ks = 0; ks < 2; ++ks) {
            const int kglob = t * 2 + ks;
            bf16x8 bw[3];
#pragma unroll
            for (int f = 0; f < 3; ++f) {
                const int cf = w * 3 + f;
                bw[f] = ld8(Wf + ((((cf >> 2) * 32 + kglob) * 4 + (cf & 3)) << 9) + l * 8);
            }
            bf16x8 xh = ld8(&xhi[t & 1][l & 15][ks * 32 + 8 * (l >> 4)]);
            bf16x8 xl = ld8(&xlo[t & 1][l & 15][ks * 32 + 8 * (l >> 4)]);
#pragma unroll
            for (int f = 0; f < 3; ++f) {
                acc[f] = mfma16(xh, bw[f], acc[f]);
                acc[f] = mfma16(xl, bw[f], acc[f]);
            }
        }
    }

    const float* bias[3] = {bq, bk, bv};
    const int rowb = row0 + 4 * (l >> 4);
    const int b = rowb >> 12, tok0 = rowb & 4095;
#pragma unroll
    for (int f = 0; f < 3; ++f) {
        const int cf = w * 3 + f;
        const int m = cf >> 2, nf = cf & 3;
        const int d = nf * 16 + (l & 15);
        const float bb = bias[m][d];
        if (m == 0) {
            const int qtile = tok0 >> 5;
            const int ksq = d >> 4, hq = (d >> 3) & 1, jq = d & 7;
#pragma unroll
            for (int r4 = 0; r4 < 4; ++r4) {
                int cq = (tok0 & 31) + r4;
                Qf[(((size_t)(b * 128 + qtile) * 4 + ksq) << 9) + (32 * hq + cq) * 8 + jq] =
                    f2bf((acc[f][r4] + bb) * QSCALE);
            }
        } else if (m == 1) {
            const int t = tok0 >> 6, tb = (tok0 >> 5) & 1;
            const int ksk = d >> 4, hk = (d >> 3) & 1, jk = d & 7;
#pragma unroll
            for (int r4 = 0; r4 < 4; ++r4) {
                int ck = (tok0 & 31) + r4;
                Kf[(((size_t)((b * 64 + t) * 8 + tb * 4 + ksk)) << 9) + (32 * hk + ck) * 8 + jk] =
                    f2bf(acc[f][r4] + bb);
            }
        } else {
            // Vf element (lane', j) = V[kv = t*64 + 16ku + 8hv + j][dv = 32td + c']
            const int t = tok0 >> 6, ku = (tok0 >> 4) & 3, hv = (tok0 >> 3) & 1, jv = tok0 & 7;
            const int cv = d & 31, td = d >> 5;
            u16x4 pk;
#pragma unroll
            for (int r4 = 0; r4 < 4; ++r4) pk[r4] = f2bf(acc[f][r4] + bb);
            *(u16x4*)(Vf + (((size_t)((b * 64 + t) * 8 + td * 4 + ku)) << 9) +
                      (32 * hv + cv) * 8 + jv) = pk;
        }
    }
}

// ---------- flash attention ----------
// 256 blocks (4 batch x 64 q-tile PAIRS {pr, 127-pr}: constant work) x 8 waves.
// batch = bid&3 -> each XCD sees one batch -> K/V L2-resident.
// Wave g handles kv tiles t = g, g+8, ... for BOTH q-tiles -> balanced per wave.
// All operand loads are 1KB coalesced ld8 from fragment-order Qf/Kf/Vf.
struct TState { float m, l; f16v o0, o1; };

__device__ __forceinline__ void run_tile(const unsigned short* __restrict__ Qf,
                                         const unsigned short* __restrict__ Kf,
                                         const unsigned short* __restrict__ Vf,
                                         int batch, int qt, int g8, int l, int h, int c,
                                         TState& st)
{
    const int NT = (qt >> 1) + 1;
    st.m = -1e30f; st.l = 0.f; st.o0 = (f16v)0.f; st.o1 = (f16v)0.f;

    bf16x8 qf[4];
    const unsigned short* qp = Qf + (((size_t)(batch * 128 + qt) * 4) << 9) + l * 8;
#pragma unroll
    for (int ks = 0; ks < 4; ++ks) qf[ks] = ld8(qp + (ks << 9));

    if (g8 >= NT) return;

    auto kload = [&](bf16x8(&kr)[2][4], int t_) {
        const unsigned short* p = Kf + (((size_t)(batch * 64 + t_) * 8) << 9) + l * 8;
#pragma unroll
        for (int tb = 0; tb < 2; ++tb)
#pragma unroll
            for (int ks = 0; ks < 4; ++ks)
                kr[tb][ks] = ld8(p + ((tb * 4 + ks) << 9));
    };

    auto body = [&](bf16x8(&kr)[2][4], bf16x8(&kn)[2][4], int t_) {
        bf16x8 vr[2][4];
        {
            const unsigned short* p = Vf + (((size_t)(batch * 64 + t_) * 8) << 9) + l * 8;
#pragma unroll
            for (int td = 0; td < 2; ++td)
#pragma unroll
                for (int ku = 0; ku < 4; ++ku)
                    vr[td][ku] = ld8(p + ((td * 4 + ku) << 9));
        }
        // S^T = K Q^T
        f16v sacc[2];
        sacc[0] = (f16v)0.f; sacc[1] = (f16v)0.f;
#pragma unroll
        for (int ks = 0; ks < 4; ++ks) {
            sacc[0] = mfma32(kr[0][ks], qf[ks], sacc[0]);
            sacc[1] = mfma32(kr[1][ks], qf[ks], sacc[1]);
        }
        int tn = t_ + 8; if (tn > NT - 1) tn = NT - 1;
        kload(kn, tn);
        if (t_ == NT - 1) {   // causal mask on diagonal tile
            const int off = qt * QB - t_ * KVB;
#pragma unroll
            for (int tb = 0; tb < 2; ++tb)
#pragma unroll
                for (int r = 0; r < 16; ++r) {
                    int mv = 32 * tb + (r & 3) + 8 * (r >> 2) + 4 * h - off;
                    if (mv > c) sacc[tb][r] = -1e30f;
                }
        }
        // online softmax (exp2 domain)
        float pm = -1e30f;
#pragma unroll
        for (int tb = 0; tb < 2; ++tb)
#pragma unroll
            for (int r = 0; r < 16; ++r) pm = fmaxf(pm, sacc[tb][r]);
        pm = fmaxf(pm, __shfl_xor(pm, 32));
        const float mnew = fmaxf(st.m, pm);
        const float sc = exp2f(st.m - mnew);
        st.m = mnew;
        float rs = 0.f;
        float p[2][16];
#pragma unroll
        for (int tb = 0; tb < 2; ++tb)
#pragma unroll
            for (int r = 0; r < 16; ++r) {
                float e = exp2f(sacc[tb][r] - mnew);
                p[tb][r] = e; rs += e;
            }
        rs += __shfl_xor(rs, 32);
        st.l = st.l * sc + rs;
#pragma unroll
        for (int r = 0; r < 16; ++r) { st.o0[r] *= sc; st.o1[r] *= sc; }
        // P (C-layout) -> frag via cvt_pk + permlane32_swap
        bf16x8 pa[4];
#pragma unroll
        for (int tb = 0; tb < 2; ++tb) {
            unsigned wp[8];
#pragma unroll
            for (int i = 0; i < 8; ++i) wp[i] = cvtpk(p[tb][2 * i], p[tb][2 * i + 1]);
            pswap(wp[0], wp[2]); pswap(wp[1], wp[3]);
            pswap(wp[4], wp[6]); pswap(wp[5], wp[7]);
            u32x4 f0 = {wp[0], wp[1], wp[2], wp[3]};
            u32x4 f1 = {wp[4], wp[5], wp[6], wp[7]};
            pa[2 * tb]     = __builtin_bit_cast(bf16x8, f0);
            pa[2 * tb + 1] = __builtin_bit_cast(bf16x8, f1);
        }
        // O^T += V^T P^T (C cols are q = c -> lane-local rescale is exact)
#pragma unroll
        for (int ku = 0; ku < 4; ++ku) {
            st.o0 = mfma32(vr[0][ku], pa[ku], st.o0);
            st.o1 = mfma32(vr[1][ku], pa[ku], st.o1);
        }
    };

    bf16x8 kA[2][4], kB[2][4];
    int t = g8;
    kload(kA, t);
    for (;;) {
        body(kA, kB, t);
        t += 8; if (t >= NT) break;
        body(kB, kA, t);
        t += 8; if (t >= NT) break;
    }
}

__global__ __launch_bounds__(512, 2)
void attn(const unsigned short* __restrict__ Qf, const unsigned short* __restrict__ Kf,
          const unsigned short* __restrict__ Vf, float* __restrict__ Yg)
{
    __shared__ float Osm[8][QB][33];
    __shared__ float Msm[2][8][QB];
    __shared__ float Lsm[2][8][QB];

    const int tid = threadIdx.x;
    const int g8 = tid >> 6, l = tid & 63, h = l >> 5, c = l & 31;
    const int batch = blockIdx.x & 3;
    const int pr = blockIdx.x >> 2;
    const int qtA = pr, qtB = 127 - pr;

    TState sB, sA;
    run_tile(Qf, Kf, Vf, batch, qtB, g8, l, h, c, sB);
    run_tile(Qf, Kf, Vf, batch, qtA, g8, l, h, c, sA);

    if (h == 0) {
        Msm[0][g8][c] = sA.m; Lsm[0][g8][c] = sA.l;
        Msm[1][g8][c] = sB.m; Lsm[1][g8][c] = sB.l;
    }

    auto write_partial = [&](const f16v& o) {
#pragma unroll
        for (int r = 0; r < 16; ++r) {
            int dd = (r & 3) + 8 * (r >> 2) + 4 * h;
            Osm[g8][c][dd] = o[r];
        }
    };
    auto merge_phase = [&](int tile, int dhalf, int qt_) {
        const int q = tid >> 4, d2 = (tid & 15) * 2;
        float mm = -1e30f;
#pragma unroll
        for (int gg = 0; gg < 8; ++gg) mm = fmaxf(mm, Msm[tile][gg][q]);
        float L = 0.f, o0 = 0.f, o1 = 0.f;
#pragma unroll
        for (int gg = 0; gg < 8; ++gg) {
            float a = exp2f(Msm[tile][gg][q] - mm);
            L += a * Lsm[tile][gg][q];
            o0 += a * Osm[gg][q][d2];
            o1 += a * Osm[gg][q][d2 + 1];
        }
        float inv = 1.f / L;
        float* yp = Yg + ((size_t)batch * TSEQ + (size_t)qt_ * QB + q) * HDIM + dhalf * 32 + d2;
        yp[0] = o0 * inv; yp[1] = o1 * inv;
    };

    write_partial(sA.o0);
    __syncthreads();
    merge_phase(0, 0, qtA);
    __syncthreads();
    write_partial(sA.o1);
    __syncthreads();
    merge_phase(0, 1, qtA);
    __syncthreads();
    write_partial(sB.o0);
    __syncthreads();
    merge_phase(1, 0, qtB);
    __syncthreads();
    write_partial(sB.o1);
    __syncthreads();
    merge_phase(1, 1, qtB);
}

extern "C" void kernel_launch(void* const* d_in, const int* in_sizes, int n_in,
                              void* d_out, int out_size, void* d_ws, size_t ws_size,
                              hipStream_t stream)
{
    const float* x  = (const float*)d_in[0];
    const float* Wq = (const float*)d_in[1];
    const float* bq = (const float*)d_in[2];
    const float* Wk = (const float*)d_in[3];
    const float* bk = (const float*)d_in[4];
    const float* Wv = (const float*)d_in[5];
    const float* bv = (const float*)d_in[6];
    float* y = (float*)d_out;

    unsigned short* Qb = (unsigned short*)d_ws;          // 4*128*4*512 = 1M bf16
    unsigned short* Kb = Qb + (size_t)1048576;           // 4*64*8*512  = 1M bf16
    unsigned short* Vb = Kb + (size_t)1048576;           // 1M bf16
    unsigned short* Wf = Vb + (size_t)1048576;           // 196608 bf16

    prep_wf<<<768, 256, 0, stream>>>(Wq, Wk, Wv, Wf);
    proj_qkv<<<1024, 256, 0, stream>>>(x, Wf, bq, bk, bv, Qb, Kb, Vb);
    attn<<<256, 512, 0, stream>>>(Qb, Kb, Vb, y);
}